// Round 10
// baseline (225.810 us; speedup 1.0000x reference)
//
#include <hip/hip_runtime.h>
#include <stdint.h>

typedef unsigned short u16;
typedef unsigned int   u32;

typedef __bf16 bf16x8 __attribute__((ext_vector_type(8)));
typedef float  fx4    __attribute__((ext_vector_type(4)));
typedef u16    u16x8  __attribute__((ext_vector_type(8)));
typedef u16    u16x4  __attribute__((ext_vector_type(4)));

typedef __attribute__((address_space(1))) unsigned int as1_u32;
typedef __attribute__((address_space(3))) unsigned int as3_u32;

// async global->LDS, 16B per lane. LDS dest is wave-uniform base + lane*16.
__device__ __forceinline__ void gload_lds16(const void* g, void* lds) {
  __builtin_amdgcn_global_load_lds((const as1_u32*)(uintptr_t)g,
                                   (as3_u32*)(uintptr_t)lds, 16, 0, 0);
}

__device__ __forceinline__ float b2f(u32 bits) {
  union { u32 i; float f; } v; v.i = bits << 16; return v.f;
}
__device__ __forceinline__ u16 f2b(float f) {
  union { float f; u32 i; } v; v.f = f;
  u32 x = v.i;
  return (u16)((x + 0x7fffu + ((x >> 16) & 1u)) >> 16);  // RNE (sw)
}
// hardware bf16 convert (compiler lowers to native cvt on gfx950).
__device__ __forceinline__ u16 f2b_hw(float f) {
  union { __bf16 b; u16 u; } v; v.b = (__bf16)f; return v.u;
}
// raw v_exp_f32: computes 2^x. (__exp2f collides with glibc math.h -- r8.)
__device__ __forceinline__ float exp2_hw(float f) {
  return __builtin_amdgcn_exp2f(f);
}

// ---------------------------------------------------------------------------
// Cast f32 -> bf16 for x, Wq, Wk, Wv, Wo into contiguous ws regions.
// ---------------------------------------------------------------------------
__global__ __launch_bounds__(256) void cast_kernel(
    const float* __restrict__ s0, const float* __restrict__ s1,
    const float* __restrict__ s2, const float* __restrict__ s3,
    const float* __restrict__ s4, u16* __restrict__ dst)
{
  const size_t i8 = ((size_t)blockIdx.x * 256 + threadIdx.x) * 8;
  if (i8 >= 14680064) return;
  const float* src; size_t off;
  if      (i8 <  4194304) { src = s0; off = i8; }
  else if (i8 <  8388608) { src = s1; off = i8 - 4194304; }
  else if (i8 <  9437184) { src = s2; off = i8 - 8388608; }
  else if (i8 < 10485760) { src = s3; off = i8 - 9437184; }
  else                    { src = s4; off = i8 - 10485760; }
  const float4 a = *(const float4*)(src + off);
  const float4 b = *(const float4*)(src + off + 4);
  u16x8 o;
  o[0] = f2b(a.x); o[1] = f2b(a.y); o[2] = f2b(a.z); o[3] = f2b(a.w);
  o[4] = f2b(b.x); o[5] = f2b(b.y); o[6] = f2b(b.z); o[7] = f2b(b.w);
  *(u16x8*)(dst + i8) = o;
}

// ---------------------------------------------------------------------------
// bf16 MFMA GEMM: C[M,N] = A[M,K] * B[N,K]^T, fp32 accum.
// ROUND-20: BK=64 (KT=32). r9 counters: 840 cy/iter measured vs ~250 cy
// throughput floor (LDS 192 + MFMA 80) at ~1 block/CU -- iterations are
// latency/sync-bound (barrier + ds_read latency chain), so halve their
// count. 4 bufs x 32KB = 128KB LDS, 3-ahead staging (lead ~3 iters >
// 900cy HBM latency; r14 lesson), exact vmcnt ladder 8/4/0
// (4 gloads/thread/stage). 8 waves / 512 threads, wave-tile 32x64,
// 128x128 block tile (r17-verified).
// Swizzle (8-chunk rows now): stage writes LDS linearly, global src chunk
// = c ^ (row&7); frag read chunk = (kk*4+quad) ^ (l16&7). 16-lane phase
// covers all 32 banks at 2-way (free). Conflicts were 0 at BK=32; the
// full 3-bit XOR keeps them 0 at 128B row stride.
// XCD remap: m0 from (lin&7) so each XCD's ~32 resident blocks share 2
// A-panels (1MB, L2-resident) -> A-stage loads are L2 hits. Bijective for
// gridDim.y=16 (both gemms).
// MODE 0: QKV epilogue -- RoPE fused on f32 acc for Q (2^-3*log2e
//         pre-scale, so attn uses bare v_exp_f32=2^x) and K; V cols
//         stored TRANSPOSED directly to vt.
// MODE 1: plain f32 store (output projection).
// ---------------------------------------------------------------------------
template <int MODE>
__global__ __launch_bounds__(512) void gemm_bt(
    const u16* __restrict__ A, const u16* __restrict__ B0,
    const u16* __restrict__ B1, const u16* __restrict__ B2,
    void* __restrict__ Cv, int K, int split1, int split2, int ldc,
    const float* __restrict__ cosb, const float* __restrict__ sinb,
    u16* __restrict__ vtg)
{
  __shared__ __align__(16) u16 smem[4 * 16384];  // 4 bufs x (A 16KB + B 16KB)

  // XCD-aware remap: xcd = lin&7 owns m-rows {2*xcd, 2*xcd+1}
  const int lin = (int)(blockIdx.y * gridDim.x + blockIdx.x);
  const int xcd = lin & 7, jj = lin >> 3;
  const int n0 = (jj >> 1) * 128;
  const int m0 = (xcd * 2 + (jj & 1)) * 128;

  const u16* Bsel; int nb;
  if (n0 < split1)      { Bsel = B0; nb = n0; }
  else if (n0 < split2) { Bsel = B1; nb = n0 - split1; }
  else                  { Bsel = B2; nb = n0 - split2; }

  const int tid  = threadIdx.x;
  const int wave = tid >> 6, lane = tid & 63;
  const int wm = wave >> 1, wn = wave & 1;     // wave tile: 32 rows x 64 cols
  const int quad = lane >> 4, l16 = lane & 15;

  fx4 acc[2][4];
#pragma unroll
  for (int i = 0; i < 2; ++i)
#pragma unroll
    for (int j = 0; j < 4; ++j) acc[i][j] = fx4{0.f, 0.f, 0.f, 0.f};

  // staging: 128 rows x 8 chunks(16B) per matrix = 1024 chunks; 2/thread.
  const int srow = tid >> 3;           // 0..63 (+64 for i=1)
  const int sch  = tid & 7;
  const int scs  = (sch ^ (srow & 7)) * 8;   // pre-swizzled global chunk
                                             // (row+64 ≡ row mod 8)
  auto stage = [&](int kt, int buf) {
    u16* As = smem + buf * 16384;
    u16* Bs = As + 8192;
    const int k0 = kt * 64;
#pragma unroll
    for (int i = 0; i < 2; ++i) {
      const int r = srow + i * 64;
      const int s = tid + i * 512;
      gload_lds16(A    + (size_t)(m0 + r) * K + k0 + scs, As + s * 8);
      gload_lds16(Bsel + (size_t)(nb + r) * K + k0 + scs, Bs + s * 8);
    }
  };

  const int KT = K >> 6;               // = 32 for all our shapes
  stage(0, 0); stage(1, 1); stage(2, 2);

  const int xm = l16 & 7;              // frag-read swizzle mask

#pragma unroll 1
  for (int kt = 0; kt < KT; ++kt) {
    const int rem = KT - 1 - kt;       // stages newer than kt still issued
    // stage kt complete; up to 2 newer stages (4 loads/thread each) may fly
    if (rem >= 2)      asm volatile("s_waitcnt vmcnt(8)\n\ts_barrier" ::: "memory");
    else if (rem == 1) asm volatile("s_waitcnt vmcnt(4)\n\ts_barrier" ::: "memory");
    else               asm volatile("s_waitcnt vmcnt(0)\n\ts_barrier" ::: "memory");
    if (kt + 3 < KT) stage(kt + 3, (kt + 3) & 3);  // (kt+3)&3 == (kt-1)&3:
                                                   // consumed, waves past barrier

    const u16* As = smem + (kt & 3) * 16384;
    const u16* Bs = As + 8192;

    bf16x8 af[2][2], bfr[4][2];
#pragma unroll
    for (int kk = 0; kk < 2; ++kk) {
      const int co = ((kk * 4 + quad) ^ xm) * 8;
#pragma unroll
      for (int t = 0; t < 2; ++t)
        af[t][kk]  = *(const bf16x8*)&As[(wm * 32 + t * 16 + l16) * 64 + co];
#pragma unroll
      for (int t = 0; t < 4; ++t)
        bfr[t][kk] = *(const bf16x8*)&Bs[(wn * 64 + t * 16 + l16) * 64 + co];
    }
#pragma unroll
    for (int kk = 0; kk < 2; ++kk)
#pragma unroll
      for (int ti = 0; ti < 2; ++ti)
#pragma unroll
        for (int tj = 0; tj < 4; ++tj)
          acc[ti][tj] = __builtin_amdgcn_mfma_f32_16x16x32_bf16(
              af[ti][kk], bfr[tj][kk], acc[ti][tj], 0, 0, 0);
  }

  if (MODE == 1) {                     // plain f32 store (out-proj)
    float* C = (float*)Cv;
#pragma unroll
    for (int ti = 0; ti < 2; ++ti) {
      const int row_b = m0 + wm * 32 + ti * 16 + quad * 4;
#pragma unroll
      for (int tj = 0; tj < 4; ++tj) {
        const int col = n0 + wn * 64 + tj * 16 + l16;
#pragma unroll
        for (int r = 0; r < 4; ++r)
          C[(size_t)(row_b + r) * ldc + col] = acc[ti][tj][r];
      }
    }
  } else {                             // QKV epilogue
    u16* C = (u16*)Cv;
    const int cb = n0 + wn * 64;       // wave's 64-col span = one head block
    if (cb < 2560) {                   // Q or K: fuse RoPE
      // Q: 2^-3 (1/sqrt(D)) * log2(e) so attn can use v_exp_f32 (=2^x)
      const float qs = (cb < 2048) ? 0.18033688f : 1.0f;
#pragma unroll
      for (int ti = 0; ti < 2; ++ti) {
#pragma unroll
        for (int r = 0; r < 4; ++r) {
          const int s = m0 + wm * 32 + ti * 16 + quad * 4 + r;
          const float* cr = cosb + s * 64;
          const float* sr = sinb + s * 64;
          u16* orow = C + (size_t)s * 3072 + cb;
#pragma unroll
          for (int tj = 0; tj < 2; ++tj) {
            const int d0 = tj * 16 + l16, d1 = d0 + 32;
            const float x0 = acc[ti][tj][r], x1 = acc[ti][tj + 2][r];
            orow[d0] = f2b((x0 * cr[d0] - x1 * sr[d0]) * qs);
            orow[d1] = f2b((x1 * cr[d1] + x0 * sr[d1]) * qs);
          }
        }
      }
    } else {                           // V: store TRANSPOSED to vt[d][key]
      const int vr0 = cb - 2560;
#pragma unroll
      for (int ti = 0; ti < 2; ++ti) {
        const int s0 = m0 + wm * 32 + ti * 16 + quad * 4;
#pragma unroll
        for (int tj = 0; tj < 4; ++tj) {
          const int vr = vr0 + tj * 16 + l16;
          u16x4 o;
#pragma unroll
          for (int r = 0; r < 4; ++r) o[r] = f2b(acc[ti][tj][r]);
          *(u16x4*)(vtg + (size_t)vr * 2048 + s0) = o;
        }
      }
    }
  }
}

// ---------------------------------------------------------------------------
// MFMA causal flash attention (r19 schedule, unchanged this round):
// KV-head-localized XCD remap (bi&7 = kvh -> per-XCD K+V 512KB L2-resident),
// exp2 softmax (log2e folded into Q by gemm), linear [64]-stride LDS + XOR
// chunk swizzle, async gload_lds staging w/ source pre-swizzle, depth-1
// double-buffered 64-key halves, 48KB LDS (3 blk/CU), s_setprio on MFMA.
// Verified MFMA layouts: A: m=lane&15,k=quad*8+j; C/D: col=lane&15,row=quad*4+r.
// Ps is per-wave (in-wave DS ordering), no barrier around it.
// ---------------------------------------------------------------------------
__global__ __launch_bounds__(256) void attn_kernel(
    const u16* __restrict__ qkv, const u16* __restrict__ vt,
    u16* __restrict__ attnbuf)
{
  const int bi  = blockIdx.x;
  const int kvh = bi & 7;                  // XCD-local kv head
  const int j   = bi >> 3;                 // 0..127
  const int h   = kvh * 4 + (j & 3);       // head
  const int bx  = 31 - (j >> 2);           // q-tile, heaviest first
  const int tid = threadIdx.x;
  const int w = tid >> 6, lane = tid & 63;
  const int quad = lane >> 4, l16 = lane & 15;

  __shared__ __align__(16) u16 Qs[64 * 64];
  __shared__ __align__(16) u16 Kb[2][64 * 64];
  __shared__ __align__(16) u16 Vb[2][64 * 64];
  __shared__ __align__(16) u16 Ps[4][16 * 64];

  const int r0    = bx * 64;
  const int nhalf = bx + 1;                // 64-key halves to process
  const int kcol  = 2048 + kvh * 64;

  const int srow = tid >> 3;               // 0..31 (i=1 adds 32)
  const int sc   = tid & 7;

  auto stageQ = [&]() {
#pragma unroll
    for (int i = 0; i < 2; ++i) {
      const int r  = srow + i * 32;
      const int cs = sc ^ (r & 7);
      gload_lds16(qkv + (size_t)(r0 + r) * 3072 + h * 64 + cs * 8,
                  Qs + (size_t)(tid + i * 256) * 8);
    }
  };
  auto stageKV = [&](int n) {
    const int k0 = n * 64;
    u16* Kd = Kb[n & 1];
    u16* Vd = Vb[n & 1];
#pragma unroll
    for (int i = 0; i < 2; ++i) {
      const int r  = srow + i * 32;
      const int cs = sc ^ (r & 7);
      gload_lds16(qkv + (size_t)(k0 + r) * 3072 + kcol + cs * 8,
                  Kd + (size_t)(tid + i * 256) * 8);
      gload_lds16(vt + (size_t)(kvh * 64 + r) * 2048 + k0 + cs * 8,
                  Vd + (size_t)(tid + i * 256) * 8);
    }
  };

  stageQ();
  stageKV(0);
  asm volatile("s_waitcnt vmcnt(0)\n\ts_barrier" ::: "memory");

  // Q fragments hoisted out of the tile loop (row = w*16+l16, row&7 = l16&7)
  const int xm = l16 & 7;                  // swizzle mask for frag reads
  const int qrow = w * 16 + l16;
  const bf16x8 aq0 = *(const bf16x8*)&Qs[qrow * 64 + ((quad    ) ^ xm) * 8];
  const bf16x8 aq1 = *(const bf16x8*)&Qs[qrow * 64 + ((4 + quad) ^ xm) * 8];

  fx4 O[4];
  float l_r[4];
#pragma unroll
  for (int c = 0; c < 4; ++c) O[c] = fx4{0.f, 0.f, 0.f, 0.f};
#pragma unroll
  for (int r = 0; r < 4; ++r) l_r[r] = 0.f;

#pragma unroll 1
  for (int n = 0; n < nhalf; ++n) {
    if (n + 1 < nhalf) stageKV(n + 1);     // async, lands before next barrier
    const u16* Kh = Kb[n & 1];
    const u16* Vd = Vb[n & 1];
    const int k0h = n * 64;

    // QK^T: scores for 16 q-rows x 64 keys
    fx4 sc4[4];
    __builtin_amdgcn_s_setprio(1);
#pragma unroll
    for (int c = 0; c < 4; ++c) {
      const int kr = c * 16 + l16;
      const bf16x8 b0 = *(const bf16x8*)&Kh[kr * 64 + ((quad    ) ^ xm) * 8];
      const bf16x8 b1 = *(const bf16x8*)&Kh[kr * 64 + ((4 + quad) ^ xm) * 8];
      fx4 z = fx4{0.f, 0.f, 0.f, 0.f};
      z      = __builtin_amdgcn_mfma_f32_16x16x32_bf16(aq0, b0, z, 0, 0, 0);
      sc4[c] = __builtin_amdgcn_mfma_f32_16x16x32_bf16(aq1, b1, z, 0, 0, 0);
    }
    __builtin_amdgcn_s_setprio(0);

    // p = exp2(s) (log2e folded into Q); causal mask only on the diagonal
    // half (k0h == r0). Ps write XOR-swizzled on the u16 column index.
    if (k0h >= r0) {
#pragma unroll
      for (int c = 0; c < 4; ++c)
#pragma unroll
        for (int r = 0; r < 4; ++r) {
          float p = exp2_hw(sc4[c][r]);
          if (k0h + c * 16 + l16 > r0 + w * 16 + quad * 4 + r) p = 0.f;
          l_r[r] += p;
          const int pr = quad * 4 + r;
          Ps[w][pr * 64 + ((c * 16 + l16) ^ ((pr & 7) << 3))] = f2b_hw(p);
        }
    } else {
#pragma unroll
      for (int c = 0; c < 4; ++c)
#pragma unroll
        for (int r = 0; r < 4; ++r) {
          const float p = exp2_hw(sc4[c][r]);
          l_r[r] += p;
          const int pr = quad * 4 + r;
          Ps[w][pr * 64 + ((c * 16 + l16) ^ ((pr & 7) << 3))] = f2b_hw(p);
        }
    }

    // PV: O[16q x 64d] += P[16q x 64k] * V^T[64d x 64k]
    const bf16x8 ap0 = *(const bf16x8*)&Ps[w][l16 * 64 + ((quad    ) ^ xm) * 8];
    const bf16x8 ap1 = *(const bf16x8*)&Ps[w][l16 * 64 + ((4 + quad) ^ xm) * 8];
    __builtin_amdgcn_s_setprio(1);
#pragma unroll
    for (int c = 0; c < 4; ++c) {
      const int vr = c * 16 + l16;
      const bf16x8 v0 = *(const bf16x8*)&Vd[vr * 64 + ((quad    ) ^ xm) * 8];
      const bf16x8 v1 = *(const bf16x8*)&Vd[vr * 64 + ((4 + quad) ^ xm) * 8];
      O[c] = __builtin_amdgcn_mfma_f32_16x16x32_bf16(ap0, v0, O[c], 0, 0, 0);
      O[c] = __builtin_amdgcn_mfma_f32_16x16x32_bf16(ap1, v1, O[c], 0, 0, 0);
    }
    __builtin_amdgcn_s_setprio(0);

    // next half's stage landed + all waves done reading this half's bufs
    asm volatile("s_waitcnt vmcnt(0)\n\ts_barrier" ::: "memory");
  }

  // epilogue: reduce l across the 16 lanes of the quad, divide, store
#pragma unroll
  for (int r = 0; r < 4; ++r) {
    float l = l_r[r];
#pragma unroll
    for (int off = 1; off < 16; off <<= 1) l += __shfl_xor(l, off, 64);
    const float inv = 1.f / fmaxf(l, 1e-30f);
    const int qg = r0 + w * 16 + quad * 4 + r;
#pragma unroll
    for (int c = 0; c < 4; ++c)
      attnbuf[(size_t)qg * 2048 + h * 64 + c * 16 + l16] = f2b(O[c][r] * inv);
  }
}

// ---------------------------------------------------------------------------
extern "C" void kernel_launch(void* const* d_in, const int* in_sizes, int n_in,
                              void* d_out, int out_size, void* d_ws, size_t ws_size,
                              hipStream_t stream) {
  const float* x    = (const float*)d_in[0];
  const float* Wq   = (const float*)d_in[1];
  const float* Wk   = (const float*)d_in[2];
  const float* Wv   = (const float*)d_in[3];
  const float* Wo   = (const float*)d_in[4];
  const float* cosb = (const float*)d_in[5];
  const float* sinb = (const float*)d_in[6];
  // d_in[7] = attn_mask (causal, applied structurally); d_in[8] = last_pos (=S)
  float* out = (float*)d_out;

  u16* ws      = (u16*)d_ws;
  u16* qkv     = ws;                          // 2048x3072 bf16 (Q scaled+roped, K roped)
  u16* attnbuf = ws + 6291456;                // 2048x2048 bf16
  u16* xb      = ws + 10485760;               // 2048x2048 bf16
  u16* Wqb     = ws + 14680064;               // 2048x2048
  u16* Wkb     = ws + 18874368;               //  512x2048
  u16* Wvb     = ws + 19922944;               //  512x2048
  u16* Wob     = ws + 20971520;               // 2048x2048
  u16* vtg     = ws + 25165824;               //  512x2048 (V^T per kv head)

  // 1) cast inputs to bf16
  cast_kernel<<<7168, 256, 0, stream>>>(x, Wq, Wk, Wv, Wo, xb);

  // 2) QKV projection + fused RoPE/Q-scale + fused V-transpose
  gemm_bt<0><<<dim3(24, 16), 512, 0, stream>>>(
      xb, Wqb, Wkb, Wvb, qkv, 2048, 2048, 2560, 3072, cosb, sinb, vtg);

  // 3) causal MFMA flash attention: 1024 blocks, XCD-localized kv heads
  attn_kernel<<<1024, 256, 0, stream>>>(qkv, vtg, attnbuf);

  // 4) output projection (f32 out)
  gemm_bt<1><<<dim3(16, 16), 512, 0, stream>>>(
      attnbuf, Wob, Wob, Wob, out, 2048, 1 << 30, 1 << 30, 2048, cosb, sinb, vtg);
}

// Round 11
// 217.239 us; speedup vs baseline: 1.0395x; 1.0395x over previous
//
#include <hip/hip_runtime.h>
#include <stdint.h>

typedef unsigned short u16;
typedef unsigned int   u32;

typedef __bf16 bf16x8 __attribute__((ext_vector_type(8)));
typedef float  fx4    __attribute__((ext_vector_type(4)));
typedef float  f32x16 __attribute__((ext_vector_type(16)));
typedef u16    u16x8  __attribute__((ext_vector_type(8)));
typedef u16    u16x4  __attribute__((ext_vector_type(4)));

typedef __attribute__((address_space(1))) unsigned int as1_u32;
typedef __attribute__((address_space(3))) unsigned int as3_u32;

// async global->LDS, 16B per lane. LDS dest is wave-uniform base + lane*16.
__device__ __forceinline__ void gload_lds16(const void* g, void* lds) {
  __builtin_amdgcn_global_load_lds((const as1_u32*)(uintptr_t)g,
                                   (as3_u32*)(uintptr_t)lds, 16, 0, 0);
}

__device__ __forceinline__ float b2f(u32 bits) {
  union { u32 i; float f; } v; v.i = bits << 16; return v.f;
}
__device__ __forceinline__ u16 f2b(float f) {
  union { float f; u32 i; } v; v.f = f;
  u32 x = v.i;
  return (u16)((x + 0x7fffu + ((x >> 16) & 1u)) >> 16);  // RNE (sw)
}
// hardware bf16 convert (compiler lowers to native cvt on gfx950).
__device__ __forceinline__ u16 f2b_hw(float f) {
  union { __bf16 b; u16 u; } v; v.b = (__bf16)f; return v.u;
}
// raw v_exp_f32: computes 2^x. (__exp2f collides with glibc math.h -- r8.)
__device__ __forceinline__ float exp2_hw(float f) {
  return __builtin_amdgcn_exp2f(f);
}

// ---------------------------------------------------------------------------
// Cast f32 -> bf16 for x, Wq, Wk, Wv, Wo into contiguous ws regions.
// ---------------------------------------------------------------------------
__global__ __launch_bounds__(256) void cast_kernel(
    const float* __restrict__ s0, const float* __restrict__ s1,
    const float* __restrict__ s2, const float* __restrict__ s3,
    const float* __restrict__ s4, u16* __restrict__ dst)
{
  const size_t i8 = ((size_t)blockIdx.x * 256 + threadIdx.x) * 8;
  if (i8 >= 14680064) return;
  const float* src; size_t off;
  if      (i8 <  4194304) { src = s0; off = i8; }
  else if (i8 <  8388608) { src = s1; off = i8 - 4194304; }
  else if (i8 <  9437184) { src = s2; off = i8 - 8388608; }
  else if (i8 < 10485760) { src = s3; off = i8 - 9437184; }
  else                    { src = s4; off = i8 - 10485760; }
  const float4 a = *(const float4*)(src + off);
  const float4 b = *(const float4*)(src + off + 4);
  u16x8 o;
  o[0] = f2b(a.x); o[1] = f2b(a.y); o[2] = f2b(a.z); o[3] = f2b(a.w);
  o[4] = f2b(b.x); o[5] = f2b(b.y); o[6] = f2b(b.z); o[7] = f2b(b.w);
  *(u16x8*)(dst + i8) = o;
}

// ---------------------------------------------------------------------------
// bf16 MFMA GEMM: C[M,N] = A[M,K] * B[N,K]^T, fp32 accum.
// ROUND-21: r9-exact schedule (proven 45.1us QKV: 8 waves/512thr, wave-tile
// 32x64, 128x128 block tile, BK=32, 5-buffer 4-ahead async pipeline, 80KB
// LDS = 2 blk/CU, exact vmcnt 6/4/2/0, linear block mapping) with ONE
// change: MFMA shape 16x16x32 -> 32x32x16. Measured pipe rates (m06/m119):
// 32x32 = 2382 TF vs 16x16 = 2075 TF (+15%), and per K-step 4 MFMA @8cy
// replace 8 @5cy (half the instructions, same 6 ds_read_b128) -- right
// direction for the measured latency/issue-bound regime (r9: 840cy/iter vs
// ~250cy throughput floor).
// r10 reverts: BK=64 (128KB LDS -> 1 blk/CU, occupancy 22->14, -12%) and
// XCD m-remap (FETCH 44->58MB, B-panel L2 reuse broken).
// Layouts (guide-verified): C/D col=lane&31, row=(reg&3)+8*(reg>>2)+
// 4*(lane>>5); A/B m(n)=lane&31, k=(lane>>5)*8+j. Wave tile = two 32x32
// col-tiles -> RoPE pair (d, d+32) in same lane (tile0/tile1, same reg).
// Swizzle: stage chunk c of row r holds global chunk c^((r>>1)&3); frag
// read chunk = (kk*2+(lane>>5)) ^ (((lane&31)>>1)&3). 16-lane phase covers
// all 32 banks at 2-way (free; bank-checked).
// MODE 0: QKV epilogue -- RoPE fused on f32 acc for Q (2^-3*log2e scale ->
//         attn uses bare v_exp_f32=2^x) and K; V stored TRANSPOSED to vt.
// MODE 1: plain f32 store (output projection).
// ---------------------------------------------------------------------------
template <int MODE>
__global__ __launch_bounds__(512) void gemm_bt(
    const u16* __restrict__ A, const u16* __restrict__ B0,
    const u16* __restrict__ B1, const u16* __restrict__ B2,
    void* __restrict__ Cv, int K, int split1, int split2, int ldc,
    const float* __restrict__ cosb, const float* __restrict__ sinb,
    u16* __restrict__ vtg)
{
  __shared__ __align__(16) u16 smem[5 * 8192];   // 5 bufs x (A 8KB + B 8KB)

  const int n0 = blockIdx.x * 128;
  const int m0 = blockIdx.y * 128;

  const u16* Bsel; int nb;
  if (n0 < split1)      { Bsel = B0; nb = n0; }
  else if (n0 < split2) { Bsel = B1; nb = n0 - split1; }
  else                  { Bsel = B2; nb = n0 - split2; }

  const int tid  = threadIdx.x;
  const int wave = tid >> 6, lane = tid & 63;
  const int wm = wave >> 1, wn = wave & 1;     // wave tile: 32 rows x 64 cols
  const int l32 = lane & 31, hi = lane >> 5;   // 32x32 frag coords

  f32x16 acc2[2];
#pragma unroll
  for (int t = 0; t < 2; ++t)
#pragma unroll
    for (int r = 0; r < 16; ++r) acc2[t][r] = 0.f;

  const int row = tid >> 2;            // 0..127: one 16B chunk per thread
  const int ch  = tid & 3;
  const int csw = (ch ^ ((row >> 1) & 3)) * 8;   // pre-swizzled global chunk
  auto stage = [&](int kt, int buf) {
    u16* As = smem + buf * 8192;
    u16* Bs = As + 4096;
    const int k0 = kt * 32;
    gload_lds16(A    + (size_t)(m0 + row) * K + k0 + csw, As + tid * 8);
    gload_lds16(Bsel + (size_t)(nb + row) * K + k0 + csw, Bs + tid * 8);
  };

  const int KT = K >> 5;               // = 64 for all our shapes
  stage(0, 0); stage(1, 1); stage(2, 2); stage(3, 3);
  int bufR = 0, bufW = 4;              // rotating mod-5 buffer counters

  // frag-read swizzle: f(row) = (row>>1)&3 = ((lane&31)>>1)&3 (bases ≡ 0 mod 4)
  const int fx = (l32 >> 1) & 3;

#pragma unroll 1
  for (int kt = 0; kt < KT; ++kt) {
    const int rem = KT - 1 - kt;       // stages newer than kt still issued
    // stage kt complete; up to 3 newer stages (2 loads/thread each) may fly
    if (rem >= 3)      asm volatile("s_waitcnt vmcnt(6)\n\ts_barrier" ::: "memory");
    else if (rem == 2) asm volatile("s_waitcnt vmcnt(4)\n\ts_barrier" ::: "memory");
    else if (rem == 1) asm volatile("s_waitcnt vmcnt(2)\n\ts_barrier" ::: "memory");
    else               asm volatile("s_waitcnt vmcnt(0)\n\ts_barrier" ::: "memory");
    if (kt + 4 < KT) stage(kt + 4, bufW);  // bufW == buf read at kt-1:
                                           // consumed, all waves past barrier

    const u16* As = smem + bufR * 8192;
    const u16* Bs = As + 4096;

    bf16x8 a[2], b[2][2];              // [kk], [tile][kk]
#pragma unroll
    for (int kk = 0; kk < 2; ++kk) {
      const int co = ((kk * 2 + hi) ^ fx) * 8;   // swizzled chunk offset
      a[kk]    = *(const bf16x8*)&As[(wm * 32 + l32) * 32 + co];
      b[0][kk] = *(const bf16x8*)&Bs[(wn * 64 + l32) * 32 + co];
      b[1][kk] = *(const bf16x8*)&Bs[(wn * 64 + 32 + l32) * 32 + co];
    }
#pragma unroll
    for (int kk = 0; kk < 2; ++kk)
#pragma unroll
      for (int t = 0; t < 2; ++t)
        acc2[t] = __builtin_amdgcn_mfma_f32_32x32x16_bf16(
            a[kk], b[t][kk], acc2[t], 0, 0, 0);

    bufR = (bufR == 4) ? 0 : bufR + 1;
    bufW = (bufW == 4) ? 0 : bufW + 1;
  }

  // C/D layout: col = lane&31 (+t*32), row = (reg&3) + 8*(reg>>2) + 4*hi
  if (MODE == 1) {                     // plain f32 store (out-proj)
    float* C = (float*)Cv;
    const int colb = n0 + wn * 64 + l32;
#pragma unroll
    for (int t = 0; t < 2; ++t)
#pragma unroll
      for (int reg = 0; reg < 16; ++reg) {
        const int s = m0 + wm * 32 + (reg & 3) + 8 * (reg >> 2) + 4 * hi;
        C[(size_t)s * ldc + colb + t * 32] = acc2[t][reg];
      }
  } else {                             // QKV epilogue
    u16* C = (u16*)Cv;
    const int cb = n0 + wn * 64;       // wave's 64-col span = one head block
    if (cb < 2560) {                   // Q or K: fuse RoPE
      // Q: 2^-3 (1/sqrt(D)) * log2(e) so attn can use v_exp_f32 (=2^x)
      const float qs = (cb < 2048) ? 0.18033688f : 1.0f;
      const int d0 = l32, d1 = l32 + 32;
#pragma unroll
      for (int reg = 0; reg < 16; ++reg) {
        const int s = m0 + wm * 32 + (reg & 3) + 8 * (reg >> 2) + 4 * hi;
        const float* cr = cosb + s * 64;
        const float* sr = sinb + s * 64;
        u16* orow = C + (size_t)s * 3072 + cb;
        const float x0 = acc2[0][reg], x1 = acc2[1][reg];
        orow[d0] = f2b((x0 * cr[d0] - x1 * sr[d0]) * qs);
        orow[d1] = f2b((x1 * cr[d1] + x0 * sr[d1]) * qs);
      }
    } else {                           // V: store TRANSPOSED to vt[d][key]
      const int vr0 = cb - 2560 + l32;
#pragma unroll
      for (int t = 0; t < 2; ++t) {
        const int vr = vr0 + t * 32;
#pragma unroll
        for (int rg = 0; rg < 4; ++rg) {
          const int s0 = m0 + wm * 32 + 8 * rg + 4 * hi;
          u16x4 o;
#pragma unroll
          for (int r = 0; r < 4; ++r) o[r] = f2b(acc2[t][rg * 4 + r]);
          *(u16x4*)(vtg + (size_t)vr * 2048 + s0) = o;
        }
      }
    }
  }
}

// ---------------------------------------------------------------------------
// MFMA causal flash attention (r19 schedule, unchanged):
// KV-head-localized XCD remap (bi&7 = kvh -> per-XCD K+V 512KB L2-resident),
// exp2 softmax (log2e folded into Q by gemm), linear [64]-stride LDS + XOR
// chunk swizzle, async gload_lds staging w/ source pre-swizzle, depth-1
// double-buffered 64-key halves, 48KB LDS (3 blk/CU), s_setprio on MFMA.
// Verified MFMA layouts: A: m=lane&15,k=quad*8+j; C/D: col=lane&15,row=quad*4+r.
// Ps is per-wave (in-wave DS ordering), no barrier around it.
// ---------------------------------------------------------------------------
__global__ __launch_bounds__(256) void attn_kernel(
    const u16* __restrict__ qkv, const u16* __restrict__ vt,
    u16* __restrict__ attnbuf)
{
  const int bi  = blockIdx.x;
  const int kvh = bi & 7;                  // XCD-local kv head
  const int j   = bi >> 3;                 // 0..127
  const int h   = kvh * 4 + (j & 3);       // head
  const int bx  = 31 - (j >> 2);           // q-tile, heaviest first
  const int tid = threadIdx.x;
  const int w = tid >> 6, lane = tid & 63;
  const int quad = lane >> 4, l16 = lane & 15;

  __shared__ __align__(16) u16 Qs[64 * 64];
  __shared__ __align__(16) u16 Kb[2][64 * 64];
  __shared__ __align__(16) u16 Vb[2][64 * 64];
  __shared__ __align__(16) u16 Ps[4][16 * 64];

  const int r0    = bx * 64;
  const int nhalf = bx + 1;                // 64-key halves to process
  const int kcol  = 2048 + kvh * 64;

  const int srow = tid >> 3;               // 0..31 (i=1 adds 32)
  const int sc   = tid & 7;

  auto stageQ = [&]() {
#pragma unroll
    for (int i = 0; i < 2; ++i) {
      const int r  = srow + i * 32;
      const int cs = sc ^ (r & 7);
      gload_lds16(qkv + (size_t)(r0 + r) * 3072 + h * 64 + cs * 8,
                  Qs + (size_t)(tid + i * 256) * 8);
    }
  };
  auto stageKV = [&](int n) {
    const int k0 = n * 64;
    u16* Kd = Kb[n & 1];
    u16* Vd = Vb[n & 1];
#pragma unroll
    for (int i = 0; i < 2; ++i) {
      const int r  = srow + i * 32;
      const int cs = sc ^ (r & 7);
      gload_lds16(qkv + (size_t)(k0 + r) * 3072 + kcol + cs * 8,
                  Kd + (size_t)(tid + i * 256) * 8);
      gload_lds16(vt + (size_t)(kvh * 64 + r) * 2048 + k0 + cs * 8,
                  Vd + (size_t)(tid + i * 256) * 8);
    }
  };

  stageQ();
  stageKV(0);
  asm volatile("s_waitcnt vmcnt(0)\n\ts_barrier" ::: "memory");

  // Q fragments hoisted out of the tile loop (row = w*16+l16, row&7 = l16&7)
  const int xm = l16 & 7;                  // swizzle mask for frag reads
  const int qrow = w * 16 + l16;
  const bf16x8 aq0 = *(const bf16x8*)&Qs[qrow * 64 + ((quad    ) ^ xm) * 8];
  const bf16x8 aq1 = *(const bf16x8*)&Qs[qrow * 64 + ((4 + quad) ^ xm) * 8];

  fx4 O[4];
  float l_r[4];
#pragma unroll
  for (int c = 0; c < 4; ++c) O[c] = fx4{0.f, 0.f, 0.f, 0.f};
#pragma unroll
  for (int r = 0; r < 4; ++r) l_r[r] = 0.f;

#pragma unroll 1
  for (int n = 0; n < nhalf; ++n) {
    if (n + 1 < nhalf) stageKV(n + 1);     // async, lands before next barrier
    const u16* Kh = Kb[n & 1];
    const u16* Vd = Vb[n & 1];
    const int k0h = n * 64;

    // QK^T: scores for 16 q-rows x 64 keys
    fx4 sc4[4];
    __builtin_amdgcn_s_setprio(1);
#pragma unroll
    for (int c = 0; c < 4; ++c) {
      const int kr = c * 16 + l16;
      const bf16x8 b0 = *(const bf16x8*)&Kh[kr * 64 + ((quad    ) ^ xm) * 8];
      const bf16x8 b1 = *(const bf16x8*)&Kh[kr * 64 + ((4 + quad) ^ xm) * 8];
      fx4 z = fx4{0.f, 0.f, 0.f, 0.f};
      z      = __builtin_amdgcn_mfma_f32_16x16x32_bf16(aq0, b0, z, 0, 0, 0);
      sc4[c] = __builtin_amdgcn_mfma_f32_16x16x32_bf16(aq1, b1, z, 0, 0, 0);
    }
    __builtin_amdgcn_s_setprio(0);

    // p = exp2(s) (log2e folded into Q); causal mask only on the diagonal
    // half (k0h == r0). Ps write XOR-swizzled on the u16 column index.
    if (k0h >= r0) {
#pragma unroll
      for (int c = 0; c < 4; ++c)
#pragma unroll
        for (int r = 0; r < 4; ++r) {
          float p = exp2_hw(sc4[c][r]);
          if (k0h + c * 16 + l16 > r0 + w * 16 + quad * 4 + r) p = 0.f;
          l_r[r] += p;
          const int pr = quad * 4 + r;
          Ps[w][pr * 64 + ((c * 16 + l16) ^ ((pr & 7) << 3))] = f2b_hw(p);
        }
    } else {
#pragma unroll
      for (int c = 0; c < 4; ++c)
#pragma unroll
        for (int r = 0; r < 4; ++r) {
          const float p = exp2_hw(sc4[c][r]);
          l_r[r] += p;
          const int pr = quad * 4 + r;
          Ps[w][pr * 64 + ((c * 16 + l16) ^ ((pr & 7) << 3))] = f2b_hw(p);
        }
    }

    // PV: O[16q x 64d] += P[16q x 64k] * V^T[64d x 64k]
    const bf16x8 ap0 = *(const bf16x8*)&Ps[w][l16 * 64 + ((quad    ) ^ xm) * 8];
    const bf16x8 ap1 = *(const bf16x8*)&Ps[w][l16 * 64 + ((4 + quad) ^ xm) * 8];
    __builtin_amdgcn_s_setprio(1);
#pragma unroll
    for (int c = 0; c < 4; ++c) {
      const int vr = c * 16 + l16;
      const bf16x8 v0 = *(const bf16x8*)&Vd[vr * 64 + ((quad    ) ^ xm) * 8];
      const bf16x8 v1 = *(const bf16x8*)&Vd[vr * 64 + ((4 + quad) ^ xm) * 8];
      O[c] = __builtin_amdgcn_mfma_f32_16x16x32_bf16(ap0, v0, O[c], 0, 0, 0);
      O[c] = __builtin_amdgcn_mfma_f32_16x16x32_bf16(ap1, v1, O[c], 0, 0, 0);
    }
    __builtin_amdgcn_s_setprio(0);

    // next half's stage landed + all waves done reading this half's bufs
    asm volatile("s_waitcnt vmcnt(0)\n\ts_barrier" ::: "memory");
  }

  // epilogue: reduce l across the 16 lanes of the quad, divide, store
#pragma unroll
  for (int r = 0; r < 4; ++r) {
    float l = l_r[r];
#pragma unroll
    for (int off = 1; off < 16; off <<= 1) l += __shfl_xor(l, off, 64);
    const float inv = 1.f / fmaxf(l, 1e-30f);
    const int qg = r0 + w * 16 + quad * 4 + r;
#pragma unroll
    for (int c = 0; c < 4; ++c)
      attnbuf[(size_t)qg * 2048 + h * 64 + c * 16 + l16] = f2b(O[c][r] * inv);
  }
}

// ---------------------------------------------------------------------------
extern "C" void kernel_launch(void* const* d_in, const int* in_sizes, int n_in,
                              void* d_out, int out_size, void* d_ws, size_t ws_size,
                              hipStream_t stream) {
  const float* x    = (const float*)d_in[0];
  const float* Wq   = (const float*)d_in[1];
  const float* Wk   = (const float*)d_in[2];
  const float* Wv   = (const float*)d_in[3];
  const float* Wo   = (const float*)d_in[4];
  const float* cosb = (const float*)d_in[5];
  const float* sinb = (const float*)d_in[6];
  // d_in[7] = attn_mask (causal, applied structurally); d_in[8] = last_pos (=S)
  float* out = (float*)d_out;

  u16* ws      = (u16*)d_ws;
  u16* qkv     = ws;                          // 2048x3072 bf16 (Q scaled+roped, K roped)
  u16* attnbuf = ws + 6291456;                // 2048x2048 bf16
  u16* xb      = ws + 10485760;               // 2048x2048 bf16
  u16* Wqb     = ws + 14680064;               // 2048x2048
  u16* Wkb     = ws + 18874368;               //  512x2048
  u16* Wvb     = ws + 19922944;               //  512x2048
  u16* Wob     = ws + 20971520;               // 2048x2048
  u16* vtg     = ws + 25165824;               //  512x2048 (V^T per kv head)

  // 1) cast inputs to bf16
  cast_kernel<<<7168, 256, 0, stream>>>(x, Wq, Wk, Wv, Wo, xb);

  // 2) QKV projection + fused RoPE/Q-scale + fused V-transpose
  gemm_bt<0><<<dim3(24, 16), 512, 0, stream>>>(
      xb, Wqb, Wkb, Wvb, qkv, 2048, 2048, 2560, 3072, cosb, sinb, vtg);

  // 3) causal MFMA flash attention: 1024 blocks, XCD-localized kv heads
  attn_kernel<<<1024, 256, 0, stream>>>(qkv, vtg, attnbuf);

  // 4) output projection (f32 out)
  gemm_bt<1><<<dim3(16, 16), 512, 0, stream>>>(
      attnbuf, Wob, Wob, Wob, out, 2048, 1 << 30, 1 << 30, 2048, cosb, sinb, vtg);
}

// Round 12
// 209.871 us; speedup vs baseline: 1.0759x; 1.0351x over previous
//
#include <hip/hip_runtime.h>
#include <stdint.h>

typedef unsigned short u16;
typedef unsigned int   u32;

typedef __bf16 bf16x8 __attribute__((ext_vector_type(8)));
typedef float  fx4    __attribute__((ext_vector_type(4)));
typedef u16    u16x8  __attribute__((ext_vector_type(8)));
typedef u16    u16x4  __attribute__((ext_vector_type(4)));

typedef __attribute__((address_space(1))) unsigned int as1_u32;
typedef __attribute__((address_space(3))) unsigned int as3_u32;

// async global->LDS, 16B per lane. LDS dest is wave-uniform base + lane*16.
__device__ __forceinline__ void gload_lds16(const void* g, void* lds) {
  __builtin_amdgcn_global_load_lds((const as1_u32*)(uintptr_t)g,
                                   (as3_u32*)(uintptr_t)lds, 16, 0, 0);
}

__device__ __forceinline__ float b2f(u32 bits) {
  union { u32 i; float f; } v; v.i = bits << 16; return v.f;
}
__device__ __forceinline__ u16 f2b(float f) {
  union { float f; u32 i; } v; v.f = f;
  u32 x = v.i;
  return (u16)((x + 0x7fffu + ((x >> 16) & 1u)) >> 16);  // RNE (sw)
}
// hardware bf16 convert (compiler lowers to native cvt on gfx950).
__device__ __forceinline__ u16 f2b_hw(float f) {
  union { __bf16 b; u16 u; } v; v.b = (__bf16)f; return v.u;
}
// raw v_exp_f32: computes 2^x. (__exp2f collides with glibc math.h -- r8.)
__device__ __forceinline__ float exp2_hw(float f) {
  return __builtin_amdgcn_exp2f(f);
}
// packed f32x2 -> bf16x2 convert: dst.lo = cvt(a), dst.hi = cvt(b).
__device__ __forceinline__ u32 cvtpk_bf16(float a, float b) {
  u32 r;
  asm("v_cvt_pk_bf16_f32 %0, %1, %2" : "=v"(r) : "v"(a), "v"(b));
  return r;
}

// ---------------------------------------------------------------------------
// Cast f32 -> bf16 for x, Wq, Wk, Wv, Wo into contiguous ws regions.
// ---------------------------------------------------------------------------
__global__ __launch_bounds__(256) void cast_kernel(
    const float* __restrict__ s0, const float* __restrict__ s1,
    const float* __restrict__ s2, const float* __restrict__ s3,
    const float* __restrict__ s4, u16* __restrict__ dst)
{
  const size_t i8 = ((size_t)blockIdx.x * 256 + threadIdx.x) * 8;
  if (i8 >= 14680064) return;
  const float* src; size_t off;
  if      (i8 <  4194304) { src = s0; off = i8; }
  else if (i8 <  8388608) { src = s1; off = i8 - 4194304; }
  else if (i8 <  9437184) { src = s2; off = i8 - 8388608; }
  else if (i8 < 10485760) { src = s3; off = i8 - 9437184; }
  else                    { src = s4; off = i8 - 10485760; }
  const float4 a = *(const float4*)(src + off);
  const float4 b = *(const float4*)(src + off + 4);
  u16x8 o;
  o[0] = f2b(a.x); o[1] = f2b(a.y); o[2] = f2b(a.z); o[3] = f2b(a.w);
  o[4] = f2b(b.x); o[5] = f2b(b.y); o[6] = f2b(b.z); o[7] = f2b(b.w);
  *(u16x8*)(dst + i8) = o;
}

// ---------------------------------------------------------------------------
// bf16 MFMA GEMM: C[M,N] = A[M,K] * B[N,K]^T, fp32 accum.
// ROUND-22: exact r9 revert (proven 45.1us QKV, conflicts 0). The r10
// (BK=64: occupancy loss) and r11 (32x32x16: 4.7M bank conflicts)
// experiments both regressed; r9 config is the measured optimum.
// 8 waves / 512 threads, wave-tile 32x64 (2x4 frags of 16x16x32), 128x128
// block tile, BK=32, 5-buffer 4-ahead async gload_lds pipeline (80KB LDS,
// 2 blk/CU), exact vmcnt ladder 6/4/2/0, r13 LDS XOR swizzle.
// Q pre-scale folds 1/sqrt(D) * log2(e) so attn uses bare v_exp_f32 (=2^x).
// MODE 0: QKV epilogue -- RoPE fused on f32 acc for Q and K; V cols stored
//         TRANSPOSED directly to vt.
// MODE 1: plain f32 store (output projection).
// ---------------------------------------------------------------------------
template <int MODE>
__global__ __launch_bounds__(512) void gemm_bt(
    const u16* __restrict__ A, const u16* __restrict__ B0,
    const u16* __restrict__ B1, const u16* __restrict__ B2,
    void* __restrict__ Cv, int K, int split1, int split2, int ldc,
    const float* __restrict__ cosb, const float* __restrict__ sinb,
    u16* __restrict__ vtg)
{
  __shared__ __align__(16) u16 smem[5 * 8192];   // 5 bufs x (A 8KB + B 8KB)

  const int n0 = blockIdx.x * 128;
  const int m0 = blockIdx.y * 128;

  const u16* Bsel; int nb;
  if (n0 < split1)      { Bsel = B0; nb = n0; }
  else if (n0 < split2) { Bsel = B1; nb = n0 - split1; }
  else                  { Bsel = B2; nb = n0 - split2; }

  const int tid  = threadIdx.x;
  const int wave = tid >> 6, lane = tid & 63;
  const int wm = wave >> 1, wn = wave & 1;     // wave tile: 32 rows x 64 cols
  const int quad = lane >> 4, l16 = lane & 15;

  fx4 acc[2][4];
#pragma unroll
  for (int i = 0; i < 2; ++i)
#pragma unroll
    for (int j = 0; j < 4; ++j) acc[i][j] = fx4{0.f, 0.f, 0.f, 0.f};

  const int row = tid >> 2;            // 0..127: one 16B chunk per thread
  const int ch  = tid & 3;
  const int csw = (ch ^ ((row >> 1) & 3)) * 8;   // pre-swizzled global chunk
  auto stage = [&](int kt, int buf) {
    u16* As = smem + buf * 8192;
    u16* Bs = As + 4096;
    const int k0 = kt * 32;
    gload_lds16(A    + (size_t)(m0 + row) * K + k0 + csw, As + tid * 8);
    gload_lds16(Bsel + (size_t)(nb + row) * K + k0 + csw, Bs + tid * 8);
  };

  const int KT = K >> 5;               // = 64 for all our shapes
  stage(0, 0); stage(1, 1); stage(2, 2); stage(3, 3);
  int bufR = 0, bufW = 4;              // rotating mod-5 buffer counters

  // frag-read swizzle: f(row) = (row>>1)&3 = (l16>>1)&3 (bases = 0 mod 4)
  const int fx = (l16 >> 1) & 3;
  const int cA = (quad ^ fx) * 8;      // swizzled chunk offset (u16 units)

#pragma unroll 1
  for (int kt = 0; kt < KT; ++kt) {
    const int rem = KT - 1 - kt;       // stages newer than kt still issued
    // stage kt complete; up to 3 newer stages (2 loads/thread each) may fly
    if (rem >= 3)      asm volatile("s_waitcnt vmcnt(6)\n\ts_barrier" ::: "memory");
    else if (rem == 2) asm volatile("s_waitcnt vmcnt(4)\n\ts_barrier" ::: "memory");
    else if (rem == 1) asm volatile("s_waitcnt vmcnt(2)\n\ts_barrier" ::: "memory");
    else               asm volatile("s_waitcnt vmcnt(0)\n\ts_barrier" ::: "memory");
    if (kt + 4 < KT) stage(kt + 4, bufW);  // bufW == buf read at kt-1:
                                           // consumed, all waves past barrier

    const u16* As = smem + bufR * 8192;
    const u16* Bs = As + 4096;

    bf16x8 af[2], bfr[4];
#pragma unroll
    for (int t = 0; t < 2; ++t)
      af[t]  = *(const bf16x8*)&As[(wm * 32 + t * 16 + l16) * 32 + cA];
#pragma unroll
    for (int t = 0; t < 4; ++t)
      bfr[t] = *(const bf16x8*)&Bs[(wn * 64 + t * 16 + l16) * 32 + cA];
#pragma unroll
    for (int ti = 0; ti < 2; ++ti)
#pragma unroll
      for (int tj = 0; tj < 4; ++tj)
        acc[ti][tj] = __builtin_amdgcn_mfma_f32_16x16x32_bf16(
            af[ti], bfr[tj], acc[ti][tj], 0, 0, 0);

    bufR = (bufR == 4) ? 0 : bufR + 1;
    bufW = (bufW == 4) ? 0 : bufW + 1;
  }

  if (MODE == 1) {                     // plain f32 store (out-proj)
    float* C = (float*)Cv;
#pragma unroll
    for (int ti = 0; ti < 2; ++ti) {
      const int row_b = m0 + wm * 32 + ti * 16 + quad * 4;
#pragma unroll
      for (int tj = 0; tj < 4; ++tj) {
        const int col = n0 + wn * 64 + tj * 16 + l16;
#pragma unroll
        for (int r = 0; r < 4; ++r)
          C[(size_t)(row_b + r) * ldc + col] = acc[ti][tj][r];
      }
    }
  } else {                             // QKV epilogue
    u16* C = (u16*)Cv;
    const int cb = n0 + wn * 64;       // wave's 64-col span = one head block
    if (cb < 2560) {                   // Q or K: fuse RoPE
      // Q: 2^-3 (1/sqrt(D)) * log2(e) so attn can use v_exp_f32 (=2^x)
      const float qs = (cb < 2048) ? 0.18033688f : 1.0f;
#pragma unroll
      for (int ti = 0; ti < 2; ++ti) {
#pragma unroll
        for (int r = 0; r < 4; ++r) {
          const int s = m0 + wm * 32 + ti * 16 + quad * 4 + r;
          const float* cr = cosb + s * 64;
          const float* sr = sinb + s * 64;
          u16* orow = C + (size_t)s * 3072 + cb;
#pragma unroll
          for (int tj = 0; tj < 2; ++tj) {
            const int d0 = tj * 16 + l16, d1 = d0 + 32;
            const float x0 = acc[ti][tj][r], x1 = acc[ti][tj + 2][r];
            orow[d0] = f2b((x0 * cr[d0] - x1 * sr[d0]) * qs);
            orow[d1] = f2b((x1 * cr[d1] + x0 * sr[d1]) * qs);
          }
        }
      }
    } else {                           // V: store TRANSPOSED to vt[d][key]
      const int vr0 = cb - 2560;
#pragma unroll
      for (int ti = 0; ti < 2; ++ti) {
        const int s0 = m0 + wm * 32 + ti * 16 + quad * 4;
#pragma unroll
        for (int tj = 0; tj < 4; ++tj) {
          const int vr = vr0 + tj * 16 + l16;
          u16x4 o;
#pragma unroll
          for (int r = 0; r < 4; ++r) o[r] = f2b(acc[ti][tj][r]);
          *(u16x4*)(vtg + (size_t)vr * 2048 + s0) = o;
        }
      }
    }
  }
}

// ---------------------------------------------------------------------------
// MFMA causal flash attention.
// ROUND-22: swapped-operand QK^T + in-register softmax + packed-u32 Ps.
// DS-pipe arithmetic (r11 analysis): per wave-half the old code issued 18
// ds_read_b128 + 16 scalar ds_write_u16 (~1100 LDS-pipe cy per block-half
// x 66 block-halves/CU ~= 30us of the 45us kernel) -- the DS pipe is the
// dominant resource. Changes:
//  * QK^T computes mfma(K,Q) (operand swap -- LDS reads are byte-identical;
//    only output layout flips): lane now holds P[key=c*16+quad*4+r][q=l16].
//  * exp/mask in-register; pack pairs with v_cvt_pk_bf16_f32 (8 ops replace
//    16 f2b) and store 4 ds_write_b64 (replaces 16 ds_write_u16).
//  * Ps is u32[16 q-rows][32]: pair-chunk swizzle chunk2 ^= (l16&7)<<1
//    (pair-preserving -> b64 writes + b128 reads stay aligned; bank-checked
//    conflict-free). PV A-frag (m=q=lane&15) reads ap0/ap1 b128 as before.
//  * denominator: one scalar accumulator; end butterfly shfl_xor(16,32)
//    gives l(q=l16); epilogue pulls inv per O-row via 4 shfls.
// r19 structure otherwise: KV-head-localized XCD remap (bi&7=kvh -> per-XCD
// K+V 512KB L2-resident), exp2 softmax (log2e folded into Q), linear LDS +
// XOR chunk swizzle, async gload_lds staging, depth-1 double-buffered
// 64-key halves, 48KB LDS (3 blk/CU), s_setprio on MFMA clusters.
// Verified MFMA layouts: A/B: m(n)=lane&15, k=quad*8+j; C/D: col=lane&15
// (B-operand index), row=quad*4+reg (A-operand index).
// Ps is per-wave (in-wave DS ordering), no barrier around it.
// ---------------------------------------------------------------------------
__global__ __launch_bounds__(256) void attn_kernel(
    const u16* __restrict__ qkv, const u16* __restrict__ vt,
    u16* __restrict__ attnbuf)
{
  const int bi  = blockIdx.x;
  const int kvh = bi & 7;                  // XCD-local kv head
  const int j   = bi >> 3;                 // 0..127
  const int h   = kvh * 4 + (j & 3);       // head
  const int bx  = 31 - (j >> 2);           // q-tile, heaviest first
  const int tid = threadIdx.x;
  const int w = tid >> 6, lane = tid & 63;
  const int quad = lane >> 4, l16 = lane & 15;

  __shared__ __align__(16) u16 Qs[64 * 64];
  __shared__ __align__(16) u16 Kb[2][64 * 64];
  __shared__ __align__(16) u16 Vb[2][64 * 64];
  __shared__ __align__(16) u32 Ps[4][16 * 32];   // packed bf16x2, per wave

  const int r0    = bx * 64;
  const int nhalf = bx + 1;                // 64-key halves to process
  const int kcol  = 2048 + kvh * 64;

  const int srow = tid >> 3;               // 0..31 (i=1 adds 32)
  const int sc   = tid & 7;

  auto stageQ = [&]() {
#pragma unroll
    for (int i = 0; i < 2; ++i) {
      const int r  = srow + i * 32;
      const int cs = sc ^ (r & 7);
      gload_lds16(qkv + (size_t)(r0 + r) * 3072 + h * 64 + cs * 8,
                  Qs + (size_t)(tid + i * 256) * 8);
    }
  };
  auto stageKV = [&](int n) {
    const int k0 = n * 64;
    u16* Kd = Kb[n & 1];
    u16* Vd = Vb[n & 1];
#pragma unroll
    for (int i = 0; i < 2; ++i) {
      const int r  = srow + i * 32;
      const int cs = sc ^ (r & 7);
      gload_lds16(qkv + (size_t)(k0 + r) * 3072 + kcol + cs * 8,
                  Kd + (size_t)(tid + i * 256) * 8);
      gload_lds16(vt + (size_t)(kvh * 64 + r) * 2048 + k0 + cs * 8,
                  Vd + (size_t)(tid + i * 256) * 8);
    }
  };

  stageQ();
  stageKV(0);
  asm volatile("s_waitcnt vmcnt(0)\n\ts_barrier" ::: "memory");

  // Q fragments hoisted out of the tile loop (row = w*16+l16, row&7 = l16&7)
  const int xm = l16 & 7;                  // swizzle mask for frag reads
  const int qrow = w * 16 + l16;
  const bf16x8 aq0 = *(const bf16x8*)&Qs[qrow * 64 + ((quad    ) ^ xm) * 8];
  const bf16x8 aq1 = *(const bf16x8*)&Qs[qrow * 64 + ((4 + quad) ^ xm) * 8];

  fx4 O[4];
  float l_acc = 0.f;
#pragma unroll
  for (int c = 0; c < 4; ++c) O[c] = fx4{0.f, 0.f, 0.f, 0.f};

  const int s2 = (l16 & 7) << 1;           // Ps pair-chunk swizzle

#pragma unroll 1
  for (int n = 0; n < nhalf; ++n) {
    if (n + 1 < nhalf) stageKV(n + 1);     // async, lands before next barrier
    const u16* Kh = Kb[n & 1];
    const u16* Vd = Vb[n & 1];
    const int k0h = n * 64;

    // QK^T swapped: sc4[c][r] = S[key = k0h + c*16 + quad*4 + r][q = l16]
    fx4 sc4[4];
    __builtin_amdgcn_s_setprio(1);
#pragma unroll
    for (int c = 0; c < 4; ++c) {
      const int kr = c * 16 + l16;
      const bf16x8 b0 = *(const bf16x8*)&Kh[kr * 64 + ((quad    ) ^ xm) * 8];
      const bf16x8 b1 = *(const bf16x8*)&Kh[kr * 64 + ((4 + quad) ^ xm) * 8];
      fx4 z = fx4{0.f, 0.f, 0.f, 0.f};
      z      = __builtin_amdgcn_mfma_f32_16x16x32_bf16(b0, aq0, z, 0, 0, 0);
      sc4[c] = __builtin_amdgcn_mfma_f32_16x16x32_bf16(b1, aq1, z, 0, 0, 0);
    }
    __builtin_amdgcn_s_setprio(0);

    // p = exp2(s) in-register; causal mask only on the diagonal half.
    const int qg16 = r0 + w * 16 + l16;    // this lane's q
    if (k0h >= r0) {
#pragma unroll
      for (int c = 0; c < 4; ++c)
#pragma unroll
        for (int r = 0; r < 4; ++r) {
          float p = exp2_hw(sc4[c][r]);
          if (k0h + c * 16 + quad * 4 + r > qg16) p = 0.f;
          l_acc += p;
          sc4[c][r] = p;
        }
    } else {
#pragma unroll
      for (int c = 0; c < 4; ++c)
#pragma unroll
        for (int r = 0; r < 4; ++r) {
          const float p = exp2_hw(sc4[c][r]);
          l_acc += p;
          sc4[c][r] = p;
        }
    }

    // pack + store: lane(l16,quad) holds keys c*16+quad*4+0..3 of q=l16.
    // u32 pair-chunk chunk2 = c*4+quad, swizzled ^s2 (even -> b64/b128 ok).
#pragma unroll
    for (int c = 0; c < 4; ++c) {
      const u32 lo = cvtpk_bf16(sc4[c][0], sc4[c][1]);
      const u32 hi = cvtpk_bf16(sc4[c][2], sc4[c][3]);
      const int c2 = (c * 4 + quad) ^ s2;
      *(uint2*)&Ps[w][l16 * 32 + 2 * c2] = uint2{lo, hi};
    }

    // PV: O[16q x 64d] += P[16q x 64k] * V^T[64d x 64k]
    // A-frag: m=q=lane&15 (row l16), k=keys quad*8+j -> logical chunk2
    // {2quad, 2quad+1} (ap0), {8+2quad, ...} (ap1), phys = ^s2.
    const bf16x8 ap0 = *(const bf16x8*)&Ps[w][l16 * 32 + 2 * ((2 * quad    ) ^ s2)];
    const bf16x8 ap1 = *(const bf16x8*)&Ps[w][l16 * 32 + 2 * ((8 + 2 * quad) ^ s2)];
    __builtin_amdgcn_s_setprio(1);
#pragma unroll
    for (int c = 0; c < 4; ++c) {
      const int vr = c * 16 + l16;
      const bf16x8 v0 = *(const bf16x8*)&Vd[vr * 64 + ((quad    ) ^ xm) * 8];
      const bf16x8 v1 = *(const bf16x8*)&Vd[vr * 64 + ((4 + quad) ^ xm) * 8];
      O[c] = __builtin_amdgcn_mfma_f32_16x16x32_bf16(ap0, v0, O[c], 0, 0, 0);
      O[c] = __builtin_amdgcn_mfma_f32_16x16x32_bf16(ap1, v1, O[c], 0, 0, 0);
    }
    __builtin_amdgcn_s_setprio(0);

    // next half's stage landed + all waves done reading this half's bufs
    asm volatile("s_waitcnt vmcnt(0)\n\ts_barrier" ::: "memory");
  }

  // epilogue: l(q=l16) = butterfly over quads; redistribute inv to O rows
  float l = l_acc;
  l += __shfl_xor(l, 16, 64);
  l += __shfl_xor(l, 32, 64);
  const float inv = 1.f / fmaxf(l, 1e-30f);
#pragma unroll
  for (int r = 0; r < 4; ++r) {
    const float iv = __shfl(inv, (lane & 48) | (quad * 4 + r), 64);
    const int qg = r0 + w * 16 + quad * 4 + r;
#pragma unroll
    for (int c = 0; c < 4; ++c)
      attnbuf[(size_t)qg * 2048 + h * 64 + c * 16 + l16] = f2b(O[c][r] * iv);
  }
}

// ---------------------------------------------------------------------------
extern "C" void kernel_launch(void* const* d_in, const int* in_sizes, int n_in,
                              void* d_out, int out_size, void* d_ws, size_t ws_size,
                              hipStream_t stream) {
  const float* x    = (const float*)d_in[0];
  const float* Wq   = (const float*)d_in[1];
  const float* Wk   = (const float*)d_in[2];
  const float* Wv   = (const float*)d_in[3];
  const float* Wo   = (const float*)d_in[4];
  const float* cosb = (const float*)d_in[5];
  const float* sinb = (const float*)d_in[6];
  // d_in[7] = attn_mask (causal, applied structurally); d_in[8] = last_pos (=S)
  float* out = (float*)d_out;

  u16* ws      = (u16*)d_ws;
  u16* qkv     = ws;                          // 2048x3072 bf16 (Q scaled+roped, K roped)
  u16* attnbuf = ws + 6291456;                // 2048x2048 bf16
  u16* xb      = ws + 10485760;               // 2048x2048 bf16
  u16* Wqb     = ws + 14680064;               // 2048x2048
  u16* Wkb     = ws + 18874368;               //  512x2048
  u16* Wvb     = ws + 19922944;               //  512x2048
  u16* Wob     = ws + 20971520;               // 2048x2048
  u16* vtg     = ws + 25165824;               //  512x2048 (V^T per kv head)

  // 1) cast inputs to bf16
  cast_kernel<<<7168, 256, 0, stream>>>(x, Wq, Wk, Wv, Wo, xb);

  // 2) QKV projection + fused RoPE/Q-scale + fused V-transpose
  gemm_bt<0><<<dim3(24, 16), 512, 0, stream>>>(
      xb, Wqb, Wkb, Wvb, qkv, 2048, 2048, 2560, 3072, cosb, sinb, vtg);

  // 3) causal MFMA flash attention: 1024 blocks, XCD-localized kv heads
  attn_kernel<<<1024, 256, 0, stream>>>(qkv, vtg, attnbuf);

  // 4) output projection (f32 out)
  gemm_bt<1><<<dim3(16, 16), 512, 0, stream>>>(
      attnbuf, Wob, Wob, Wob, out, 2048, 1 << 30, 1 << 30, 2048, cosb, sinb, vtg);
}